// Round 1
// baseline (678.285 us; speedup 1.0000x reference)
//
#include <hip/hip_runtime.h>

#define D 128
#define NUM_GRAPHS 4096

// One wave per row. Lane l owns columns {2l, 2l+1} (float2).
// batch is sorted -> graph id is wave-uniform and changes rarely; accumulate
// weighted sums in registers, flush with atomicAdd only on graph change.
__global__ __launch_bounds__(256) void attn_agg_accum(
    const float* __restrict__ H, const int* __restrict__ batch,
    const float* __restrict__ w, const float* __restrict__ b,
    float* __restrict__ S /* d_out used as accumulator [NUM_GRAPHS*D] */,
    float* __restrict__ Z /* [NUM_GRAPHS] */,
    int V)
{
    const int lane = threadIdx.x & 63;
    const int waves_per_block = blockDim.x >> 6;
    const int wave_id = blockIdx.x * waves_per_block + (threadIdx.x >> 6);
    const int total_waves = gridDim.x * waves_per_block;
    const int rows_per_wave = (V + total_waves - 1) / total_waves;

    int row0 = wave_id * rows_per_wave;
    int row1 = row0 + rows_per_wave;
    if (row1 > V) row1 = V;
    if (row0 >= row1) return;

    const float2 w2 = ((const float2*)w)[lane];
    const float bias = b[0];

    float2 acc = make_float2(0.f, 0.f);
    float zacc = 0.f;
    int cur_g = batch[row0];

    for (int v = row0; v < row1; ++v) {
        const float2 h2 = ((const float2*)(H + (size_t)v * D))[lane];
        const int g = batch[v];          // wave-uniform (all lanes same v)

        if (g != cur_g) {                // wave-uniform branch, rare (~1/123 iters)
            atomicAdd(&S[(size_t)cur_g * D + 2 * lane],     acc.x);
            atomicAdd(&S[(size_t)cur_g * D + 2 * lane + 1], acc.y);
            if (lane == 0) atomicAdd(&Z[cur_g], zacc);
            acc = make_float2(0.f, 0.f);
            zacc = 0.f;
            cur_g = g;
        }

        // per-lane partial dot, then wave-wide butterfly reduce (width 64)
        float dot = h2.x * w2.x + h2.y * w2.y;
        #pragma unroll
        for (int off = 32; off > 0; off >>= 1)
            dot += __shfl_xor(dot, off, 64);

        const float logit = __expf(dot + bias);
        acc.x += logit * h2.x;
        acc.y += logit * h2.y;
        zacc  += logit;
    }
    // final flush
    atomicAdd(&S[(size_t)cur_g * D + 2 * lane],     acc.x);
    atomicAdd(&S[(size_t)cur_g * D + 2 * lane + 1], acc.y);
    if (lane == 0) atomicAdd(&Z[cur_g], zacc);
}

__global__ __launch_bounds__(256) void attn_agg_norm(
    float* __restrict__ out, const float* __restrict__ Z, int n)
{
    const int i = blockIdx.x * blockDim.x + threadIdx.x;
    if (i < n) {
        const int g = i >> 7;            // D == 128
        out[i] = out[i] / Z[g];
    }
}

extern "C" void kernel_launch(void* const* d_in, const int* in_sizes, int n_in,
                              void* d_out, int out_size, void* d_ws, size_t ws_size,
                              hipStream_t stream) {
    const float* H     = (const float*)d_in[0];
    const int*   batch = (const int*)  d_in[1];
    const float* w     = (const float*)d_in[2];
    const float* b     = (const float*)d_in[3];
    float* out = (float*)d_out;          // [NUM_GRAPHS, D] accumulator + result
    float* Z   = (float*)d_ws;           // [NUM_GRAPHS]

    const int V = in_sizes[0] / D;       // 1,000,000

    // d_out / d_ws are poisoned 0xAA before every launch -> zero them here.
    hipMemsetAsync(out, 0, (size_t)out_size * sizeof(float), stream);
    hipMemsetAsync(Z,   0, NUM_GRAPHS * sizeof(float), stream);

    // 2048 blocks x 256 threads = 8192 waves (full 32 waves/CU occupancy),
    // each wave streams a ~123-row contiguous chunk (~63 KB).
    attn_agg_accum<<<2048, 256, 0, stream>>>(H, batch, w, b, out, Z, V);

    const int n = NUM_GRAPHS * D;
    attn_agg_norm<<<(n + 255) / 256, 256, 0, stream>>>(out, Z, n);
}

// Round 2
// 653.159 us; speedup vs baseline: 1.0385x; 1.0385x over previous
//
#include <hip/hip_runtime.h>

#define D 128
#define NUM_GRAPHS 4096

typedef float v2f __attribute__((ext_vector_type(2)));

__device__ __forceinline__ void flush_acc(float* __restrict__ S, float* __restrict__ Z,
                                          int g, int lane, v2f& acc, float& zacc) {
    atomicAdd(&S[(size_t)g * D + 2 * lane],     acc.x);
    atomicAdd(&S[(size_t)g * D + 2 * lane + 1], acc.y);
    if (lane == 0) atomicAdd(&Z[g], zacc);
    acc.x = 0.f; acc.y = 0.f;
    zacc = 0.f;
}

// One wave per row; lane l owns columns {2l, 2l+1}. 4-row batching for MLP
// (4 outstanding 512B loads/wave) + ILP-4 interleaved butterfly reduces.
// batch is sorted -> graph id wave-uniform, changes every ~244 rows; register
// accumulate, atomic flush only at graph boundaries / chunk end.
__global__ __launch_bounds__(256) void attn_agg_accum(
    const float* __restrict__ H, const int* __restrict__ batch,
    const float* __restrict__ w, const float* __restrict__ b,
    float* __restrict__ S /* [NUM_GRAPHS*D] = d_out */,
    float* __restrict__ Z /* [NUM_GRAPHS] */,
    int V)
{
    const int lane = threadIdx.x & 63;
    const int wave_id = blockIdx.x * (blockDim.x >> 6) + (threadIdx.x >> 6);
    const int total_waves = gridDim.x * (blockDim.x >> 6);
    const int rows_per_wave = (V + total_waves - 1) / total_waves;

    int row0 = wave_id * rows_per_wave;
    int row1 = row0 + rows_per_wave;
    if (row1 > V) row1 = V;
    if (row0 >= row1) return;

    const v2f w2 = ((const v2f*)w)[lane];
    const float bias = b[0];

    v2f acc; acc.x = 0.f; acc.y = 0.f;
    float zacc = 0.f;
    int cur_g = batch[row0];

    const v2f* __restrict__ Hp = (const v2f*)H;   // row v = Hp[v*64 + lane]

    int v = row0;
    for (; v + 4 <= row1; v += 4) {
        // 4 independent 512B wave-loads (keeps 4 loads in flight per wave)
        v2f h0 = __builtin_nontemporal_load(&Hp[(size_t)(v + 0) * 64 + lane]);
        v2f h1 = __builtin_nontemporal_load(&Hp[(size_t)(v + 1) * 64 + lane]);
        v2f h2 = __builtin_nontemporal_load(&Hp[(size_t)(v + 2) * 64 + lane]);
        v2f h3 = __builtin_nontemporal_load(&Hp[(size_t)(v + 3) * 64 + lane]);
        const int g0 = batch[v + 0];
        const int g1 = batch[v + 1];
        const int g2 = batch[v + 2];
        const int g3 = batch[v + 3];

        float d0 = h0.x * w2.x + h0.y * w2.y;
        float d1 = h1.x * w2.x + h1.y * w2.y;
        float d2 = h2.x * w2.x + h2.y * w2.y;
        float d3 = h3.x * w2.x + h3.y * w2.y;

        // 4 interleaved butterfly reductions across 64 lanes
        #pragma unroll
        for (int off = 32; off > 0; off >>= 1) {
            d0 += __shfl_xor(d0, off, 64);
            d1 += __shfl_xor(d1, off, 64);
            d2 += __shfl_xor(d2, off, 64);
            d3 += __shfl_xor(d3, off, 64);
        }

        const float l0 = __expf(d0 + bias);
        const float l1 = __expf(d1 + bias);
        const float l2 = __expf(d2 + bias);
        const float l3 = __expf(d3 + bias);

        if (g3 == cur_g) {               // fast path: all 4 rows in current graph
            acc.x += l0 * h0.x + l1 * h1.x + l2 * h2.x + l3 * h3.x;
            acc.y += l0 * h0.y + l1 * h1.y + l2 * h2.y + l3 * h3.y;
            zacc  += l0 + l1 + l2 + l3;
        } else {                         // graph boundary inside the quad (rare)
            if (g0 != cur_g) { flush_acc(S, Z, cur_g, lane, acc, zacc); cur_g = g0; }
            acc.x += l0 * h0.x; acc.y += l0 * h0.y; zacc += l0;
            if (g1 != cur_g) { flush_acc(S, Z, cur_g, lane, acc, zacc); cur_g = g1; }
            acc.x += l1 * h1.x; acc.y += l1 * h1.y; zacc += l1;
            if (g2 != cur_g) { flush_acc(S, Z, cur_g, lane, acc, zacc); cur_g = g2; }
            acc.x += l2 * h2.x; acc.y += l2 * h2.y; zacc += l2;
            if (g3 != cur_g) { flush_acc(S, Z, cur_g, lane, acc, zacc); cur_g = g3; }
            acc.x += l3 * h3.x; acc.y += l3 * h3.y; zacc += l3;
        }
    }

    // remainder rows (<= 3)
    for (; v < row1; ++v) {
        v2f h = __builtin_nontemporal_load(&Hp[(size_t)v * 64 + lane]);
        const int g = batch[v];
        float d = h.x * w2.x + h.y * w2.y;
        #pragma unroll
        for (int off = 32; off > 0; off >>= 1)
            d += __shfl_xor(d, off, 64);
        const float l = __expf(d + bias);
        if (g != cur_g) { flush_acc(S, Z, cur_g, lane, acc, zacc); cur_g = g; }
        acc.x += l * h.x; acc.y += l * h.y; zacc += l;
    }

    flush_acc(S, Z, cur_g, lane, acc, zacc);
}

__global__ __launch_bounds__(256) void attn_agg_norm(
    float* __restrict__ out, const float* __restrict__ Z, int n)
{
    const int i = blockIdx.x * blockDim.x + threadIdx.x;
    if (i < n) {
        const int g = i >> 7;            // D == 128
        out[i] = out[i] / Z[g];
    }
}

extern "C" void kernel_launch(void* const* d_in, const int* in_sizes, int n_in,
                              void* d_out, int out_size, void* d_ws, size_t ws_size,
                              hipStream_t stream) {
    const float* H     = (const float*)d_in[0];
    const int*   batch = (const int*)  d_in[1];
    const float* w     = (const float*)d_in[2];
    const float* b     = (const float*)d_in[3];
    float* out = (float*)d_out;          // [NUM_GRAPHS, D] accumulator + result
    float* Z   = (float*)d_ws;           // [NUM_GRAPHS]

    const int V = in_sizes[0] / D;       // 1,000,000

    hipMemsetAsync(out, 0, (size_t)out_size * sizeof(float), stream);
    hipMemsetAsync(Z,   0, NUM_GRAPHS * sizeof(float), stream);

    // 2048 blocks x 256 threads = 8192 waves; each wave streams ~123 rows.
    attn_agg_accum<<<2048, 256, 0, stream>>>(H, batch, w, b, out, Z, V);

    const int n = NUM_GRAPHS * D;
    attn_agg_norm<<<(n + 255) / 256, 256, 0, stream>>>(out, Z, n);
}

// Round 3
// 646.766 us; speedup vs baseline: 1.0487x; 1.0099x over previous
//
#include <hip/hip_runtime.h>

#define D 128
#define NUM_GRAPHS 4096

typedef float v4f __attribute__((ext_vector_type(4)));

__device__ __forceinline__ float dot4(v4f h, v4f w) {
    return h.x * w.x + h.y * w.y + h.z * w.z + h.w * w.w;
}

// Flush per-lane accumulator to global. cur_g is PER-LANE (uniform within each
// 32-lane half), so no divergent control flow is ever needed at boundaries.
__device__ __forceinline__ void flushv(float* __restrict__ S, float* __restrict__ Z,
                                       int cur_g, int colbase, bool zlane,
                                       v4f& acc, float& zacc) {
    float* p = &S[(size_t)cur_g * D + colbase];
    atomicAdd(p + 0, acc.x);
    atomicAdd(p + 1, acc.y);
    atomicAdd(p + 2, acc.z);
    atomicAdd(p + 3, acc.w);
    if (zlane) atomicAdd(&Z[cur_g], zacc);
    acc = (v4f)(0.f);
    zacc = 0.f;
}

// Layout: lane l loads float4 -> one 1KB wave-load covers TWO rows.
//   lanes 0..31  = row v   (cols 4*(l&31)..+3)
//   lanes 32..63 = row v+1
// Dot reduction: 5 butterfly steps, max offset 16 (stays within half-wave,
// DPP-friendly). Quad = 4 wave-loads = 8 rows; next quad prefetched before
// computing current (explicit software pipeline, ~4KB/wave always in flight).
__global__ __launch_bounds__(256) void attn_agg_accum(
    const float* __restrict__ H, const int* __restrict__ batch,
    const float* __restrict__ w, const float* __restrict__ b,
    float* __restrict__ S /* [NUM_GRAPHS*D] = d_out */,
    float* __restrict__ Z /* [NUM_GRAPHS] */,
    int V)
{
    const int lane    = threadIdx.x & 63;
    const int half    = lane >> 5;           // 0: even row of pair, 1: odd row
    const int colbase = (lane & 31) << 2;
    const bool zlane  = (lane & 31) == 0;

    const int wave_id     = blockIdx.x * (blockDim.x >> 6) + (threadIdx.x >> 6);
    const int total_waves = gridDim.x * (blockDim.x >> 6);
    // rows per wave, multiple of 8 so every chunk is whole quads (V=1e6 = 8*125000)
    const int rpw = ((V + total_waves * 8 - 1) / (total_waves * 8)) * 8;

    int row0 = wave_id * rpw;
    if (row0 >= V) return;
    int row1 = row0 + rpw;
    if (row1 > V) row1 = V;

    const v4f w4     = ((const v4f*)w)[lane & 31];
    const float bias = b[0];
    const v4f* __restrict__ Hp = (const v4f*)H;   // row r = Hp[r*32 + (lane&31)] per half

    v4f acc   = (v4f)(0.f);
    float zacc = 0.f;
    int cur_g = batch[row0 + half];               // per-lane (row0+1 < V since V even)

    int v = row0;
    v4f h0, h1, h2, h3;
    int g0, g1, g2, g3;
    if (v + 8 <= row1) {
        h0 = __builtin_nontemporal_load(&Hp[(size_t)(v + 0) * 32 + lane]);
        h1 = __builtin_nontemporal_load(&Hp[(size_t)(v + 2) * 32 + lane]);
        h2 = __builtin_nontemporal_load(&Hp[(size_t)(v + 4) * 32 + lane]);
        h3 = __builtin_nontemporal_load(&Hp[(size_t)(v + 6) * 32 + lane]);
        g0 = batch[v + 0 + half];
        g1 = batch[v + 2 + half];
        g2 = batch[v + 4 + half];
        g3 = batch[v + 6 + half];
    }

    while (v + 8 <= row1) {
        const int nv = v + 8;
        v4f n0 = h0, n1 = h1, n2 = h2, n3 = h3;
        int m0 = g0, m1 = g1, m2 = g2, m3 = g3;
        if (nv + 8 <= row1) {                    // prefetch next quad
            n0 = __builtin_nontemporal_load(&Hp[(size_t)(nv + 0) * 32 + lane]);
            n1 = __builtin_nontemporal_load(&Hp[(size_t)(nv + 2) * 32 + lane]);
            n2 = __builtin_nontemporal_load(&Hp[(size_t)(nv + 4) * 32 + lane]);
            n3 = __builtin_nontemporal_load(&Hp[(size_t)(nv + 6) * 32 + lane]);
            m0 = batch[nv + 0 + half];
            m1 = batch[nv + 2 + half];
            m2 = batch[nv + 4 + half];
            m3 = batch[nv + 6 + half];
        }

        float d0 = dot4(h0, w4);
        float d1 = dot4(h1, w4);
        float d2 = dot4(h2, w4);
        float d3 = dot4(h3, w4);
        #pragma unroll
        for (int off = 16; off > 0; off >>= 1) {  // stays within each half-wave
            d0 += __shfl_xor(d0, off, 64);
            d1 += __shfl_xor(d1, off, 64);
            d2 += __shfl_xor(d2, off, 64);
            d3 += __shfl_xor(d3, off, 64);
        }

        const float l0 = __expf(d0 + bias);
        const float l1 = __expf(d1 + bias);
        const float l2 = __expf(d2 + bias);
        const float l3 = __expf(d3 + bias);

        const int diff = (g0 ^ cur_g) | (g1 ^ cur_g) | (g2 ^ cur_g) | (g3 ^ cur_g);
        if (__builtin_expect(!__any(diff), 1)) {  // all 8 rows in current graphs
            acc += h0 * l0 + h1 * l1 + h2 * l2 + h3 * l3;
            zacc += l0 + l1 + l2 + l3;
        } else {                                  // boundary in quad (~1/30 iters)
            if (__any(g0 ^ cur_g)) { flushv(S, Z, cur_g, colbase, zlane, acc, zacc); cur_g = g0; }
            acc += h0 * l0; zacc += l0;
            if (__any(g1 ^ cur_g)) { flushv(S, Z, cur_g, colbase, zlane, acc, zacc); cur_g = g1; }
            acc += h1 * l1; zacc += l1;
            if (__any(g2 ^ cur_g)) { flushv(S, Z, cur_g, colbase, zlane, acc, zacc); cur_g = g2; }
            acc += h2 * l2; zacc += l2;
            if (__any(g3 ^ cur_g)) { flushv(S, Z, cur_g, colbase, zlane, acc, zacc); cur_g = g3; }
            acc += h3 * l3; zacc += l3;
        }

        h0 = n0; h1 = n1; h2 = n2; h3 = n3;
        g0 = m0; g1 = m1; g2 = m2; g3 = m3;
        v = nv;
    }

    // pair remainder (chunks are quad-multiples, but keep for safety)
    for (; v + 2 <= row1; v += 2) {
        v4f h = __builtin_nontemporal_load(&Hp[(size_t)v * 32 + lane]);
        int g = batch[v + half];
        float d = dot4(h, w4);
        #pragma unroll
        for (int off = 16; off > 0; off >>= 1)
            d += __shfl_xor(d, off, 64);
        const float l = __expf(d + bias);
        if (__any(g ^ cur_g)) { flushv(S, Z, cur_g, colbase, zlane, acc, zacc); cur_g = g; }
        acc += h * l; zacc += l;
    }

    flushv(S, Z, cur_g, colbase, zlane, acc, zacc);
}

__global__ __launch_bounds__(256) void attn_agg_norm(
    float* __restrict__ out, const float* __restrict__ Z, int n)
{
    const int i = blockIdx.x * blockDim.x + threadIdx.x;
    if (i < n) {
        const int g = i >> 7;            // D == 128
        out[i] = out[i] / Z[g];
    }
}

extern "C" void kernel_launch(void* const* d_in, const int* in_sizes, int n_in,
                              void* d_out, int out_size, void* d_ws, size_t ws_size,
                              hipStream_t stream) {
    const float* H     = (const float*)d_in[0];
    const int*   batch = (const int*)  d_in[1];
    const float* w     = (const float*)d_in[2];
    const float* b     = (const float*)d_in[3];
    float* out = (float*)d_out;          // [NUM_GRAPHS, D] accumulator + result
    float* Z   = (float*)d_ws;           // [NUM_GRAPHS]

    const int V = in_sizes[0] / D;       // 1,000,000

    hipMemsetAsync(out, 0, (size_t)out_size * sizeof(float), stream);
    hipMemsetAsync(Z,   0, NUM_GRAPHS * sizeof(float), stream);

    // 2048 blocks x 256 threads = 8192 waves; each wave streams 128 rows (16 quads)
    attn_agg_accum<<<2048, 256, 0, stream>>>(H, batch, w, b, out, Z, V);

    const int n = NUM_GRAPHS * D;
    attn_agg_norm<<<(n + 255) / 256, 256, 0, stream>>>(out, Z, n);
}